// Round 15
// baseline (126.026 us; speedup 1.0000x reference)
//
#include <hip/hip_runtime.h>
#include <type_traits>

#define N_NODES    100000
#define N_EDGES    1600000
#define NUM_REL    4
#define NUM_GRAPHS 256

constexpr int NR   = N_NODES * NUM_REL;         // 400000 segments
constexpr int NBK  = (N_NODES + 255) / 256;     // 391 buckets of 256 nodes (1024 segments)
constexpr int CAP  = 10240;                     // slots/bucket (padded mean ~8017, >8 sigma slack)
constexpr int CHK  = 8192;                      // edges per binning block
constexpr int NCH  = (N_EDGES + CHK - 1) / CHK; // 196 chunks
constexpr int CSRN = NBK * CAP;                 // 4,003,840 csr/pairs slots

typedef _Float16 half2v __attribute__((ext_vector_type(2)));
typedef _Float16 half4v __attribute__((ext_vector_type(4)));
typedef _Float16 half8v __attribute__((ext_vector_type(8)));
typedef float    f32x4  __attribute__((ext_vector_type(4)));

// ---- monotonic float<->uint encoding for atomicMax on floats ----
__device__ __forceinline__ unsigned fenc(float f) {
    unsigned u = __float_as_uint(f);
    return (u & 0x80000000u) ? ~u : (u | 0x80000000u);
}
__device__ __forceinline__ float fdec(unsigned e) {
    return __uint_as_float((e & 0x80000000u) ? (e ^ 0x80000000u) : ~e);
}

__device__ __forceinline__ void bstack_fill(const float* __restrict__ W,
                                            const float* __restrict__ root,
                                            _Float16* __restrict__ Bt,
                                            int i, int DIN, int DOUT, int SK) {
    int j = i / SK, kk = i % SK;
    float v = (kk < DIN) ? root[kk * DOUT + j]
            : (kk < 5 * DIN) ? W[(kk - DIN) * DOUT + j] : 0.f;
    Bt[j * SK + kk] = (_Float16)v;
}

// fused prep: bucket cursors, pool init, fp16-convert x, zero-rows, weight stacks,
// and pre-fill csr with the zero-row index (pad slots stay = N_NODES).
__global__ void prep_kernel(const float* __restrict__ x, _Float16* __restrict__ xh,
                            const float* __restrict__ W1, const float* __restrict__ root1, _Float16* __restrict__ Bt1,
                            const float* __restrict__ W2, const float* __restrict__ root2, _Float16* __restrict__ Bt2,
                            const float* __restrict__ W3, const float* __restrict__ root3, _Float16* __restrict__ Bt3,
                            int* __restrict__ bcur, unsigned* __restrict__ pool,
                            _Float16* __restrict__ h1, _Float16* __restrict__ h2,
                            int* __restrict__ csr) {
    int i = blockIdx.x * 256 + threadIdx.x;
    if (i < CSRN) csr[i] = N_NODES;
    if (i < N_NODES * 16) xh[i] = (_Float16)x[i];
    if (i < 512) bcur[i] = i * CAP;
    if (i < NUM_GRAPHS * 64) pool[i] = fenc(-INFINITY);
    if (i < 16 * 96)  bstack_fill(W1, root1, Bt1, i, 16, 16, 96);
    if (i < 32 * 96)  bstack_fill(W2, root2, Bt2, i, 16, 32, 96);
    if (i < 64 * 160) bstack_fill(W3, root3, Bt3, i, 32, 64, 160);
    if (i < 16) xh[(size_t)N_NODES * 16 + i] = (_Float16)0.f;
    if (i < 16) h1[(size_t)N_NODES * 16 + i] = (_Float16)0.f;
    if (i < 32) h2[(size_t)N_NODES * 32 + i] = (_Float16)0.f;
}

// partition edges into per-bucket regions (base = b*CAP): (localseg<<17) | src
__global__ __launch_bounds__(256)
void bin_kernel(const int* __restrict__ src, const int* __restrict__ dst,
                const int* __restrict__ etype, int* __restrict__ bcur,
                unsigned* __restrict__ pairs) {
    __shared__ int h[512];
    __shared__ int base[512];
    const int t = threadIdx.x;
    h[t] = 0; h[t + 256] = 0;
    __syncthreads();
    const int e0 = blockIdx.x * CHK;
    int d[CHK / 256];
#pragma unroll
    for (int k = 0; k < CHK / 256; ++k) {
        int e = e0 + k * 256 + t;
        d[k] = (e < N_EDGES) ? dst[e] : -1;
        if (d[k] >= 0) atomicAdd(&h[d[k] >> 8], 1);
    }
    __syncthreads();
    for (int b = t; b < NBK; b += 256) {
        int v = h[b];
        base[b] = v ? atomicAdd(&bcur[b], v) : 0;
        h[b] = 0;
    }
    __syncthreads();
#pragma unroll
    for (int k = 0; k < CHK / 256; ++k) {
        if (d[k] < 0) continue;
        int e = e0 + k * 256 + t;
        int b = d[k] >> 8;
        int pos = base[b] + atomicAdd(&h[b], 1);
        if (pos < (b + 1) * CAP) {            // capacity guard (statistically unreachable)
            unsigned ls = ((unsigned)(d[k] & 255) << 2) | (unsigned)etype[e];
            pairs[pos] = (unsigned)src[e] | (ls << 17);
        }
    }
}

// per-bucket LDS counting sort with 8-slot segment padding:
// csr regions 8-aligned, pad slots keep the prep-filled zero-row index.
// seginfo = {cnt, padded_start}.
__global__ __launch_bounds__(256)
void sortseg_kernel(const unsigned* __restrict__ pairs, const int* __restrict__ bcur,
                    int* __restrict__ csr, int2* __restrict__ seginfo) {
    __shared__ int hist[1024];
    __shared__ int sd[256];
    const int b = blockIdx.x;
    const int base = b * CAP;
    const int len  = min(bcur[b] - base, CAP);
    const int t = threadIdx.x;
#pragma unroll
    for (int i = 0; i < 4; ++i) hist[t * 4 + i] = 0;
    __syncthreads();
    for (int i = t; i < len; i += 256)
        atomicAdd(&hist[pairs[base + i] >> 17], 1);
    __syncthreads();
    int c0 = hist[4 * t], c1 = hist[4 * t + 1], c2 = hist[4 * t + 2], c3 = hist[4 * t + 3];
    int p0 = (c0 + 7) & ~7, p1 = (c1 + 7) & ~7, p2 = (c2 + 7) & ~7, p3 = (c3 + 7) & ~7;
    int run = p0 + p1 + p2 + p3;
    sd[t] = run;
    __syncthreads();
#pragma unroll
    for (int off = 1; off < 256; off <<= 1) {
        int a = (t >= off) ? sd[t - off] : 0;
        __syncthreads();
        sd[t] += a;
        __syncthreads();
    }
    int excl = sd[t] - run;
    int e0 = excl, e1 = excl + p0, e2 = excl + p0 + p1, e3 = excl + p0 + p1 + p2;
    hist[4 * t] = e0; hist[4 * t + 1] = e1; hist[4 * t + 2] = e2; hist[4 * t + 3] = e3;
    int seg0 = b * 1024 + 4 * t;
    if (seg0 < NR) {   // NR % 4 == 0
        *(int4*)&seginfo[seg0]     = int4{c0, base + e0, c1, base + e1};
        *(int4*)&seginfo[seg0 + 2] = int4{c2, base + e2, c3, base + e3};
    }
    __syncthreads();
    for (int i = t; i < len; i += 256) {
        unsigned p = pairs[base + i];
        int pos = atomicAdd(&hist[p >> 17], 1);   // LDS cursor from padded start
        csr[base + pos] = (int)(p & 0x1FFFFu);
    }
}

// fused layer: branch-free gather (4 lanes/segment, 8-way ILP, packed fp16 acc,
// int4 csr loads, zero-row pads) -> LDS A-tile -> MFMA -> h/pool.
template<int DIN, int DOUT, bool RELU, bool POOL>
__global__ __launch_bounds__(256)
void layer_kernel(const _Float16* __restrict__ x,   // (N_NODES+1) rows
                  const int* __restrict__ csr,      // padded, 8-aligned segments
                  const int2* __restrict__ seginfo, // {cnt, padded_start}
                  const _Float16* __restrict__ Bt,  // [DOUT][SK]
                  const float* __restrict__ bias,   // [DOUT]
                  _Float16* __restrict__ hout,      // [(N+1), DOUT] if !POOL
                  const int* __restrict__ batch,
                  unsigned* __restrict__ pool) {
    constexpr int SK  = (DIN == 16) ? 96 : 160;
    constexpr int KP  = SK + 8;
    constexpr int NPB = 16;
    constexpr int CPL = DIN / 4;
    constexpr int NP2 = CPL / 2;
    constexpr int KS  = SK / 32;
    constexpr int ROWB = DIN * 2;
    using VecT = typename std::conditional<CPL == 8, half8v, half4v>::type;

    __shared__ _Float16 sA[NPB][KP];
    __shared__ float pval[POOL ? NPB : 1][POOL ? 64 : 1];
    __shared__ int   pg[NPB];

    const int tid = threadIdx.x;

    // ---- gather into LDS ----
    {
        const int g    = tid >> 2;
        const int q    = tid & 3;
        const int nsub = g >> 2;
        const int r    = g & 3;
        const int n    = blockIdx.x * NPB + nsub;
        const int seg  = n * NUM_REL + r;
        const int2 si  = seginfo[seg];
        const int len  = si.x;
        const int start = si.y;
        const char* xb = (const char*)x;
        const int qoff = q * (ROWB / 4);

        half2v accA[NP2], accB[NP2];
#pragma unroll
        for (int p = 0; p < NP2; ++p) { accA[p] = half2v{0, 0}; accB[p] = half2v{0, 0}; }

        for (int k = 0; k < len; k += 8) {
            int4 ca = *(const int4*)&csr[start + k];
            int4 cb = *(const int4*)&csr[start + k + 4];
            const int c[8] = {ca.x, ca.y, ca.z, ca.w, cb.x, cb.y, cb.z, cb.w};
            VecT u[8];
#pragma unroll
            for (int m = 0; m < 8; ++m)
                u[m] = *(const VecT*)(xb + (c[m] * ROWB + qoff));
#pragma unroll
            for (int m = 0; m < 8; ++m) {
                const half2v* up = (const half2v*)&u[m];
#pragma unroll
                for (int p = 0; p < NP2; ++p) {
                    if (m & 1) accB[p] += up[p];
                    else       accA[p] += up[p];
                }
            }
        }
        float inv = 1.0f / fmaxf((float)len, 1.0f);
        VecT hv;
#pragma unroll
        for (int p = 0; p < NP2; ++p) {
            half2v s = accA[p] + accB[p];
            hv[2 * p]     = (_Float16)((float)s[0] * inv);
            hv[2 * p + 1] = (_Float16)((float)s[1] * inv);
        }
        *(VecT*)&sA[nsub][DIN + r * DIN + q * CPL] = hv;
        if (r == 0)
            *(VecT*)&sA[nsub][q * CPL] = *(const VecT*)(xb + (n * ROWB + qoff));
        if constexpr (SK > 5 * DIN) {
            if (r == 1 && q < 2)
                *(uint4*)&sA[nsub][5 * DIN + q * 8] = uint4{0, 0, 0, 0};
        }
        if constexpr (POOL) {
            if (tid < NPB) pg[tid] = batch[blockIdx.x * NPB + tid];
        }
    }
    __syncthreads();

    // ---- MFMA: wave w computes output j-tile w (16 cols) for all 16 rows ----
    const int w = tid >> 6, lane = tid & 63;
    const int lo16 = lane & 15, hi = lane >> 4;
    if (w * 16 < DOUT) {
        const int jt = w;
        f32x4 acc = f32x4{0.f, 0.f, 0.f, 0.f};
#pragma unroll
        for (int ks = 0; ks < KS; ++ks) {
            half8v a = *(const half8v*)&sA[lo16][ks * 32 + hi * 8];
            half8v b = *(const half8v*)&Bt[(size_t)(jt * 16 + lo16) * SK + ks * 32 + hi * 8];
            acc = __builtin_amdgcn_mfma_f32_16x16x32_f16(a, b, acc, 0, 0, 0);
        }
        float bj = bias[jt * 16 + lo16];
#pragma unroll
        for (int reg = 0; reg < 4; ++reg) {
            float v = acc[reg] + bj;
            if (RELU) v = fmaxf(v, 0.f);
            if constexpr (POOL) {
                pval[hi * 4 + reg][jt * 16 + lo16] = v;
            } else {
                hout[(size_t)(blockIdx.x * NPB + hi * 4 + reg) * DOUT + jt * 16 + lo16] = (_Float16)v;
            }
        }
    }

    // ---- fused max-pool over the block's 16 (sorted-batch) nodes ----
    if constexpr (POOL) {
        __syncthreads();
        if (tid < 64) {
            const int j = tid;
            float m = pval[0][j];
            int g0 = pg[0];
#pragma unroll
            for (int i = 1; i < NPB; ++i) {
                if (pg[i] == g0) {
                    m = fmaxf(m, pval[i][j]);
                } else {
                    atomicMax(pool + g0 * 64 + j, fenc(m));
                    g0 = pg[i];
                    m = pval[i][j];
                }
            }
            atomicMax(pool + g0 * 64 + j, fenc(m));
        }
    }
}

__global__ void decode_kernel(const unsigned* __restrict__ pool, float* __restrict__ out) {
    int i = blockIdx.x * blockDim.x + threadIdx.x;
    if (i < NUM_GRAPHS * 64) out[i] = fdec(pool[i]);
}

extern "C" void kernel_launch(void* const* d_in, const int* in_sizes, int n_in,
                              void* d_out, int out_size, void* d_ws, size_t ws_size,
                              hipStream_t stream) {
    const float* x     = (const float*)d_in[0];
    const int*   ei    = (const int*)d_in[1];
    const int*   etype = (const int*)d_in[2];
    const int*   batch = (const int*)d_in[3];
    const float* W1 = (const float*)d_in[4],  *root1 = (const float*)d_in[5],  *b1 = (const float*)d_in[6];
    const float* W2 = (const float*)d_in[7],  *root2 = (const float*)d_in[8],  *b2 = (const float*)d_in[9];
    const float* W3 = (const float*)d_in[10], *root3 = (const float*)d_in[11], *b3 = (const float*)d_in[12];
    float* out = (float*)d_out;

    const int* src = ei;
    const int* dst = ei + N_EDGES;

    // workspace layout (~48 MB), all sections 16B aligned
    int2*      seginfo = (int2*)d_ws;                       // NR {cnt, padded_start}
    int*       bcur    = (int*)(seginfo + NR);              // 512
    int*       csr     = bcur + 512;                        // CSRN + 16 pad
    unsigned*  pairs   = (unsigned*)(csr + CSRN + 16);      // CSRN
    _Float16*  xh      = (_Float16*)(pairs + CSRN);         // (N+1)*16
    _Float16*  h1      = xh + (size_t)(N_NODES + 1) * 16;   // (N+1)*16
    _Float16*  h2      = h1 + (size_t)(N_NODES + 1) * 16;   // (N+1)*32
    _Float16*  Bt1     = h2 + (size_t)(N_NODES + 1) * 32;   // 16*96
    _Float16*  Bt2     = Bt1 + 16 * 96;                     // 32*96
    _Float16*  Bt3     = Bt2 + 32 * 96;                     // 64*160
    unsigned*  pool    = (unsigned*)(Bt3 + 64 * 160);       // 256*64

    const int BT = 256;
    const int gL = N_NODES / 16;                 // fused layer blocks
    const int gP = (CSRN + BT - 1) / BT;         // prep covers csr fill (largest)

    prep_kernel<<<gP, BT, 0, stream>>>(
        x, xh, W1, root1, Bt1, W2, root2, Bt2, W3, root3, Bt3, bcur, pool, h1, h2, csr);

    bin_kernel<<<NCH, BT, 0, stream>>>(src, dst, etype, bcur, pairs);
    sortseg_kernel<<<NBK, BT, 0, stream>>>(pairs, bcur, csr, seginfo);

    layer_kernel<16, 16, true,  false><<<gL, BT, 0, stream>>>(
        xh, csr, seginfo, Bt1, b1, h1, batch, pool);
    layer_kernel<16, 32, true,  false><<<gL, BT, 0, stream>>>(
        h1, csr, seginfo, Bt2, b2, h2, batch, pool);
    layer_kernel<32, 64, false, true ><<<gL, BT, 0, stream>>>(
        h2, csr, seginfo, Bt3, b3, nullptr, batch, pool);

    decode_kernel<<<(NUM_GRAPHS * 64 + BT - 1) / BT, BT, 0, stream>>>(pool, out);
}

// Round 17
// 115.746 us; speedup vs baseline: 1.0888x; 1.0888x over previous
//
#include <hip/hip_runtime.h>
#include <type_traits>

#define N_NODES    100000
#define N_EDGES    1600000
#define NUM_REL    4
#define NUM_GRAPHS 256

constexpr int NR   = N_NODES * NUM_REL;         // 400000 segments
constexpr int NBK  = (N_NODES + 255) / 256;     // 391 buckets of 256 nodes (1024 segments)
constexpr int CAP  = 6144;                      // slots per bucket (mean 4092, sigma 64)
constexpr int CHK  = 4096;                      // edges per binning block (16 regs/thread)
constexpr int NCH  = (N_EDGES + CHK - 1) / CHK; // 391 chunks

typedef _Float16 half2v __attribute__((ext_vector_type(2)));
typedef _Float16 half4v __attribute__((ext_vector_type(4)));
typedef _Float16 half8v __attribute__((ext_vector_type(8)));
typedef float    f32x4  __attribute__((ext_vector_type(4)));

// ---- monotonic float<->uint encoding for atomicMax on floats ----
__device__ __forceinline__ unsigned fenc(float f) {
    unsigned u = __float_as_uint(f);
    return (u & 0x80000000u) ? ~u : (u | 0x80000000u);
}
__device__ __forceinline__ float fdec(unsigned e) {
    return __uint_as_float((e & 0x80000000u) ? (e ^ 0x80000000u) : ~e);
}

__device__ __forceinline__ void bstack_fill(const float* __restrict__ W,
                                            const float* __restrict__ root,
                                            _Float16* __restrict__ Bt,
                                            int i, int DIN, int DOUT, int SK) {
    int j = i / SK, kk = i % SK;
    float v = (kk < DIN) ? root[kk * DOUT + j]
            : (kk < 5 * DIN) ? W[(kk - DIN) * DOUT + j] : 0.f;
    Bt[j * SK + kk] = (_Float16)v;
}

// fused prep: bucket cursors, pool init, fp16-convert x, zero-rows, weight stacks
__global__ void prep_kernel(const float* __restrict__ x, _Float16* __restrict__ xh,
                            const float* __restrict__ W1, const float* __restrict__ root1, _Float16* __restrict__ Bt1,
                            const float* __restrict__ W2, const float* __restrict__ root2, _Float16* __restrict__ Bt2,
                            const float* __restrict__ W3, const float* __restrict__ root3, _Float16* __restrict__ Bt3,
                            int* __restrict__ bcur, unsigned* __restrict__ pool,
                            _Float16* __restrict__ h1, _Float16* __restrict__ h2) {
    int i = blockIdx.x * 256 + threadIdx.x;
    if (i < N_NODES * 16) xh[i] = (_Float16)x[i];
    if (i < 512) bcur[i] = i * CAP;
    if (i < NUM_GRAPHS * 64) pool[i] = fenc(-INFINITY);
    if (i < 16 * 96)  bstack_fill(W1, root1, Bt1, i, 16, 16, 96);
    if (i < 32 * 96)  bstack_fill(W2, root2, Bt2, i, 16, 32, 96);
    if (i < 64 * 160) bstack_fill(W3, root3, Bt3, i, 32, 64, 160);
    // zero row N of each feature table (tail-lane target)
    if (i < 16) xh[(size_t)N_NODES * 16 + i] = (_Float16)0.f;
    if (i < 16) h1[(size_t)N_NODES * 16 + i] = (_Float16)0.f;
    if (i < 32) h2[(size_t)N_NODES * 32 + i] = (_Float16)0.f;
}

// partition edges into per-bucket regions (base = b*CAP): (localseg<<17) | src
__global__ __launch_bounds__(256)
void bin_kernel(const int* __restrict__ src, const int* __restrict__ dst,
                const int* __restrict__ etype, int* __restrict__ bcur,
                unsigned* __restrict__ pairs) {
    __shared__ int h[512];
    __shared__ int base[512];
    const int t = threadIdx.x;
    h[t] = 0; h[t + 256] = 0;
    __syncthreads();
    const int e0 = blockIdx.x * CHK;
    int d[CHK / 256];
#pragma unroll
    for (int k = 0; k < CHK / 256; ++k) {
        int e = e0 + k * 256 + t;
        d[k] = (e < N_EDGES) ? dst[e] : -1;
        if (d[k] >= 0) atomicAdd(&h[d[k] >> 8], 1);
    }
    __syncthreads();
    for (int b = t; b < NBK; b += 256) {
        int v = h[b];
        base[b] = v ? atomicAdd(&bcur[b], v) : 0;
        h[b] = 0;
    }
    __syncthreads();
#pragma unroll
    for (int k = 0; k < CHK / 256; ++k) {
        if (d[k] < 0) continue;
        int e = e0 + k * 256 + t;
        int b = d[k] >> 8;
        int pos = base[b] + atomicAdd(&h[b], 1);
        if (pos < (b + 1) * CAP) {            // capacity guard (statistically unreachable)
            unsigned ls = ((unsigned)(d[k] & 255) << 2) | (unsigned)etype[e];
            pairs[pos] = (unsigned)src[e] | (ls << 17);
        }
    }
}

// per-bucket LDS counting sort: csr (bucket-region layout) + seginfo {cnt, end}
__global__ __launch_bounds__(256)
void sortseg_kernel(const unsigned* __restrict__ pairs, const int* __restrict__ bcur,
                    int* __restrict__ csr, int2* __restrict__ seginfo) {
    __shared__ int hist[1024];
    __shared__ int sd[256];
    const int b = blockIdx.x;
    const int base = b * CAP;
    const int len  = min(bcur[b] - base, CAP);
    const int t = threadIdx.x;
#pragma unroll
    for (int i = 0; i < 4; ++i) hist[t * 4 + i] = 0;
    __syncthreads();
    for (int i = t; i < len; i += 256)
        atomicAdd(&hist[pairs[base + i] >> 17], 1);
    __syncthreads();
    int c0 = hist[4 * t], c1 = hist[4 * t + 1], c2 = hist[4 * t + 2], c3 = hist[4 * t + 3];
    int run = c0 + c1 + c2 + c3;
    sd[t] = run;
    __syncthreads();
#pragma unroll
    for (int off = 1; off < 256; off <<= 1) {
        int a = (t >= off) ? sd[t - off] : 0;
        __syncthreads();
        sd[t] += a;
        __syncthreads();
    }
    int excl = sd[t] - run;
    int e0 = excl, e1 = excl + c0, e2 = excl + c0 + c1, e3 = excl + c0 + c1 + c2;
    hist[4 * t] = e0; hist[4 * t + 1] = e1; hist[4 * t + 2] = e2; hist[4 * t + 3] = e3;
    int seg0 = b * 1024 + 4 * t;
    if (seg0 < NR) {   // NR % 4 == 0
        *(int4*)&seginfo[seg0]     = int4{c0, base + e0 + c0, c1, base + e1 + c1};
        *(int4*)&seginfo[seg0 + 2] = int4{c2, base + e2 + c2, c3, base + e3 + c3};
    }
    __syncthreads();
    for (int i = t; i < len; i += 256) {
        unsigned p = pairs[base + i];
        int pos = atomicAdd(&hist[p >> 17], 1);   // LDS
        csr[base + pos] = (int)(p & 0x1FFFFu);
    }
}

// fused layer: gather (4 lanes/segment, 8-way ILP, packed fp16 accumulate)
// -> LDS A-tile -> MFMA -> h/pool. Tail lanes load the zero row (index N_NODES).
template<int DIN, int DOUT, bool RELU, bool POOL>
__global__ __launch_bounds__(256)
void layer_kernel(const _Float16* __restrict__ x,   // (N_NODES+1) rows
                  const int* __restrict__ csr,      // bucket-region layout, +16 tail pad
                  const int2* __restrict__ seginfo, // {cnt, end}
                  const _Float16* __restrict__ Bt,  // [DOUT][SK]
                  const float* __restrict__ bias,   // [DOUT]
                  _Float16* __restrict__ hout,      // [(N+1), DOUT] if !POOL
                  const int* __restrict__ batch,
                  unsigned* __restrict__ pool) {
    constexpr int SK  = (DIN == 16) ? 96 : 160;
    constexpr int KP  = SK + 8;
    constexpr int NPB = 16;
    constexpr int CPL = DIN / 4;
    constexpr int NP2 = CPL / 2;
    constexpr int KS  = SK / 32;
    constexpr int ROWB = DIN * 2;
    using VecT = typename std::conditional<CPL == 8, half8v, half4v>::type;

    __shared__ _Float16 sA[NPB][KP];
    __shared__ float pval[POOL ? NPB : 1][POOL ? 64 : 1];
    __shared__ int   pg[NPB];

    const int tid = threadIdx.x;

    // ---- gather into LDS ----
    {
        const int g    = tid >> 2;
        const int q    = tid & 3;
        const int nsub = g >> 2;
        const int r    = g & 3;
        const int n    = blockIdx.x * NPB + nsub;
        const int seg  = n * NUM_REL + r;
        const int2 si  = seginfo[seg];
        const int len  = si.x;
        const int start = si.y - len;
        const char* xb = (const char*)x;
        const int qoff = q * (ROWB / 4);

        half2v accA[NP2], accB[NP2];
#pragma unroll
        for (int p = 0; p < NP2; ++p) { accA[p] = half2v{0, 0}; accB[p] = half2v{0, 0}; }

        for (int k = 0; k < len; k += 8) {
            int lim = len - k;               // >= 1
            int c[8];
#pragma unroll
            for (int m = 0; m < 8; ++m)
                c[m] = csr[start + k + m];   // csr tail-padded; redirected below
#pragma unroll
            for (int m = 0; m < 8; ++m)
                c[m] = (m < lim) ? c[m] : N_NODES;   // zero row
            VecT u[8];
#pragma unroll
            for (int m = 0; m < 8; ++m)
                u[m] = *(const VecT*)(xb + (c[m] * ROWB + qoff));
#pragma unroll
            for (int m = 0; m < 8; ++m) {
                const half2v* up = (const half2v*)&u[m];
#pragma unroll
                for (int p = 0; p < NP2; ++p) {
                    if (m & 1) accB[p] += up[p];
                    else       accA[p] += up[p];
                }
            }
        }
        float inv = 1.0f / fmaxf((float)len, 1.0f);
        VecT hv;
#pragma unroll
        for (int p = 0; p < NP2; ++p) {
            half2v s = accA[p] + accB[p];
            hv[2 * p]     = (_Float16)((float)s[0] * inv);
            hv[2 * p + 1] = (_Float16)((float)s[1] * inv);
        }
        *(VecT*)&sA[nsub][DIN + r * DIN + q * CPL] = hv;
        if (r == 0)
            *(VecT*)&sA[nsub][q * CPL] = *(const VecT*)(xb + (n * ROWB + qoff));
        if constexpr (SK > 5 * DIN) {
            if (r == 1 && q < 2)
                *(uint4*)&sA[nsub][5 * DIN + q * 8] = uint4{0, 0, 0, 0};
        }
        if constexpr (POOL) {
            if (tid < NPB) pg[tid] = batch[blockIdx.x * NPB + tid];
        }
    }
    __syncthreads();

    // ---- MFMA: wave w computes output j-tile w (16 cols) for all 16 rows ----
    const int w = tid >> 6, lane = tid & 63;
    const int lo16 = lane & 15, hi = lane >> 4;
    if (w * 16 < DOUT) {
        const int jt = w;
        f32x4 acc = f32x4{0.f, 0.f, 0.f, 0.f};
#pragma unroll
        for (int ks = 0; ks < KS; ++ks) {
            half8v a = *(const half8v*)&sA[lo16][ks * 32 + hi * 8];
            half8v b = *(const half8v*)&Bt[(size_t)(jt * 16 + lo16) * SK + ks * 32 + hi * 8];
            acc = __builtin_amdgcn_mfma_f32_16x16x32_f16(a, b, acc, 0, 0, 0);
        }
        float bj = bias[jt * 16 + lo16];
#pragma unroll
        for (int reg = 0; reg < 4; ++reg) {
            float v = acc[reg] + bj;
            if (RELU) v = fmaxf(v, 0.f);
            if constexpr (POOL) {
                pval[hi * 4 + reg][jt * 16 + lo16] = v;
            } else {
                hout[(size_t)(blockIdx.x * NPB + hi * 4 + reg) * DOUT + jt * 16 + lo16] = (_Float16)v;
            }
        }
    }

    // ---- fused max-pool over the block's 16 (sorted-batch) nodes ----
    if constexpr (POOL) {
        __syncthreads();
        if (tid < 64) {
            const int j = tid;
            float m = pval[0][j];
            int g0 = pg[0];
#pragma unroll
            for (int i = 1; i < NPB; ++i) {
                if (pg[i] == g0) {
                    m = fmaxf(m, pval[i][j]);
                } else {
                    atomicMax(pool + g0 * 64 + j, fenc(m));
                    g0 = pg[i];
                    m = pval[i][j];
                }
            }
            atomicMax(pool + g0 * 64 + j, fenc(m));
        }
    }
}

__global__ void decode_kernel(const unsigned* __restrict__ pool, float* __restrict__ out) {
    int i = blockIdx.x * blockDim.x + threadIdx.x;
    if (i < NUM_GRAPHS * 64) out[i] = fdec(pool[i]);
}

extern "C" void kernel_launch(void* const* d_in, const int* in_sizes, int n_in,
                              void* d_out, int out_size, void* d_ws, size_t ws_size,
                              hipStream_t stream) {
    const float* x     = (const float*)d_in[0];
    const int*   ei    = (const int*)d_in[1];
    const int*   etype = (const int*)d_in[2];
    const int*   batch = (const int*)d_in[3];
    const float* W1 = (const float*)d_in[4],  *root1 = (const float*)d_in[5],  *b1 = (const float*)d_in[6];
    const float* W2 = (const float*)d_in[7],  *root2 = (const float*)d_in[8],  *b2 = (const float*)d_in[9];
    const float* W3 = (const float*)d_in[10], *root3 = (const float*)d_in[11], *b3 = (const float*)d_in[12];
    float* out = (float*)d_out;

    const int* src = ei;
    const int* dst = ei + N_EDGES;

    // workspace layout (~40 MB), all sections 16B aligned
    int2*      seginfo = (int2*)d_ws;                       // NR {cnt, end}
    int*       bcur    = (int*)(seginfo + NR);              // 512
    int*       csr     = bcur + 512;                        // NBK*CAP + 16 pad
    unsigned*  pairs   = (unsigned*)(csr + NBK * CAP + 16); // NBK*CAP
    _Float16*  xh      = (_Float16*)(pairs + NBK * CAP);    // (N+1)*16
    _Float16*  h1      = xh + (size_t)(N_NODES + 1) * 16;   // (N+1)*16
    _Float16*  h2      = h1 + (size_t)(N_NODES + 1) * 16;   // (N+1)*32
    _Float16*  Bt1     = h2 + (size_t)(N_NODES + 1) * 32;   // 16*96
    _Float16*  Bt2     = Bt1 + 16 * 96;                     // 32*96
    _Float16*  Bt3     = Bt2 + 32 * 96;                     // 64*160
    unsigned*  pool    = (unsigned*)(Bt3 + 64 * 160);       // 256*64

    const int BT = 256;
    const int gL = N_NODES / 16;            // fused layer blocks

    prep_kernel<<<(N_NODES * 16 + BT - 1) / BT, BT, 0, stream>>>(
        x, xh, W1, root1, Bt1, W2, root2, Bt2, W3, root3, Bt3, bcur, pool, h1, h2);

    bin_kernel<<<NCH, BT, 0, stream>>>(src, dst, etype, bcur, pairs);
    sortseg_kernel<<<NBK, BT, 0, stream>>>(pairs, bcur, csr, seginfo);

    layer_kernel<16, 16, true,  false><<<gL, BT, 0, stream>>>(
        xh, csr, seginfo, Bt1, b1, h1, batch, pool);
    layer_kernel<16, 32, true,  false><<<gL, BT, 0, stream>>>(
        h1, csr, seginfo, Bt2, b2, h2, batch, pool);
    layer_kernel<32, 64, false, true ><<<gL, BT, 0, stream>>>(
        h2, csr, seginfo, Bt3, b3, nullptr, batch, pool);

    decode_kernel<<<(NUM_GRAPHS * 64 + BT - 1) / BT, BT, 0, stream>>>(pool, out);
}